// Round 5
// baseline (139.651 us; speedup 1.0000x reference)
//
#include <hip/hip_runtime.h>
#include <math.h>

#define N_NODES 4096
#define F_IN    512
#define F_OUT   64
#define ALPHA   0.2f
#define NPART   32

typedef _Float16 half8 __attribute__((ext_vector_type(8)));
typedef _Float16 half4 __attribute__((ext_vector_type(4)));
typedef float    floatx4 __attribute__((ext_vector_type(4)));

// ---------------- k_prep: WT[t][k] = f16(W[k][t])  (64 x 512) ----------------
__global__ __launch_bounds__(256) void k_prep(const float* __restrict__ W,
                                              _Float16* __restrict__ WT) {
    int idx = blockIdx.x * 256 + threadIdx.x;   // 32768 total
    int t = idx >> 9;
    int k = idx & 511;
    WT[idx] = (_Float16)W[k * F_OUT + t];
}

// ---------------- k_hW: h = x@W via MFMA (K-split across 4 waves); h, hT(f16), e1 ----------------
__global__ __launch_bounds__(256) void k_hW(const float* __restrict__ x,
                                            const _Float16* __restrict__ WT,
                                            const float* __restrict__ a,
                                            float* __restrict__ h,
                                            _Float16* __restrict__ hT,
                                            float* __restrict__ e1) {
    __shared__ float red[4][16][64];   // [wave][g4*4+r][lane]
    int tid  = threadIdx.x;
    int lane = tid & 63;
    int w    = tid >> 6;
    int i0   = blockIdx.x * 16;
    int n    = lane & 15;
    int quad = lane >> 4;

    floatx4 acc[4] = {{0,0,0,0},{0,0,0,0},{0,0,0,0},{0,0,0,0}};

    const float* xr = x + (size_t)(i0 + n) * F_IN + w * 128 + quad * 8;
    const _Float16* wb = WT + w * 128 + quad * 8;
#pragma unroll
    for (int kk = 0; kk < 128; kk += 32) {
        float4 x0 = *(const float4*)(xr + kk);
        float4 x1 = *(const float4*)(xr + kk + 4);
        half8 af = {(_Float16)x0.x, (_Float16)x0.y, (_Float16)x0.z, (_Float16)x0.w,
                    (_Float16)x1.x, (_Float16)x1.y, (_Float16)x1.z, (_Float16)x1.w};
#pragma unroll
        for (int g = 0; g < 4; ++g) {
            half8 bf = *(const half8*)(wb + (size_t)(g * 16 + n) * F_IN + kk);
            acc[g] = __builtin_amdgcn_mfma_f32_16x16x32_f16(af, bf, acc[g], 0, 0, 0);
        }
    }
#pragma unroll
    for (int g = 0; g < 4; ++g)
#pragma unroll
        for (int r = 0; r < 4; ++r)
            red[w][g * 4 + r][lane] = acc[g][r];
    __syncthreads();
    if (w != 0) return;
#pragma unroll
    for (int g = 0; g < 4; ++g)
#pragma unroll
        for (int r = 0; r < 4; ++r)
            acc[g][r] = red[0][g * 4 + r][lane] + red[1][g * 4 + r][lane] +
                        red[2][g * 4 + r][lane] + red[3][g * 4 + r][lane];
#pragma unroll
    for (int g = 0; g < 4; ++g) {
        half4 hv;
#pragma unroll
        for (int r = 0; r < 4; ++r) {
            h[(size_t)(i0 + quad * 4 + r) * F_OUT + g * 16 + n] = acc[g][r];
            hv[r] = (_Float16)acc[g][r];
        }
        *(half4*)(hT + (size_t)(g * 16 + n) * N_NODES + i0 + quad * 4) = hv;
    }
    float a1v[4];
#pragma unroll
    for (int g = 0; g < 4; ++g) a1v[g] = a[g * 16 + n];
#pragma unroll
    for (int r = 0; r < 4; ++r) {
        float v = acc[0][r] * a1v[0] + acc[1][r] * a1v[1] + acc[2][r] * a1v[2] + acc[3][r] * a1v[3];
        v += __shfl_xor(v, 1, 64);
        v += __shfl_xor(v, 2, 64);
        v += __shfl_xor(v, 4, 64);
        v += __shfl_xor(v, 8, 64);
        if (n == 0) e1[i0 + quad * 4 + r] = v;
    }
}

// ---------------- k_TqP: Tq (LDS) -> P[q][j] = f16(exp(lrelu(e1[j]+Tq[j&63]))) ----------------
__global__ __launch_bounds__(256) void k_TqP(const float* __restrict__ h,
                                             const float* __restrict__ a,
                                             const float* __restrict__ e1,
                                             _Float16* __restrict__ P) {
    __shared__ float part[4][64];
    __shared__ float TqS[64];
    int q = blockIdx.x;
    int tid = threadIdx.x;
    int t = tid & 63;
    int rp = tid >> 6;
    const float* a2 = a + F_OUT;
    float s = 0.f;
#pragma unroll
    for (int rr = 0; rr < 16; ++rr) {
        int r = rp * 16 + rr;
        s += a2[r] * h[(size_t)(r * 64 + q) * F_OUT + t];
    }
    part[rp][t] = s;
    __syncthreads();
    if (tid < 64) TqS[tid] = part[0][tid] + part[1][tid] + part[2][tid] + part[3][tid];
    __syncthreads();
#pragma unroll
    for (int it = 0; it < 4; ++it) {
        int j = (it * 256 + tid) * 4;
        float4 ev = *(const float4*)(e1 + j);
        float4 tv = *(const float4*)(TqS + (j & 63));
        float e[4] = {ev.x + tv.x, ev.y + tv.y, ev.z + tv.z, ev.w + tv.w};
        half4 pv;
#pragma unroll
        for (int r = 0; r < 4; ++r) {
            float xx = e[r] > 0.f ? e[r] : ALPHA * e[r];
            pv[r] = (_Float16)__expf(xx);
        }
        *(half4*)(P + (size_t)q * N_NODES + j) = pv;
    }
}

// ---------------- k_main: 8192 waves, 128-col chunks, bounded register preload ----------------
// block b: s = b&31 (j-window, shared by the block's 4 waves for L1/L2 hT reuse),
//          g = (b>>5)*4 + w (row-group).  grid 2048 = 8 blocks/CU queued.
__global__ __launch_bounds__(256, 4) void k_main(const int* __restrict__ adj,
                                                 const _Float16* __restrict__ P,
                                                 const _Float16* __restrict__ hT,
                                                 float* __restrict__ out_part,
                                                 float* __restrict__ den_part) {
    int tid  = threadIdx.x;
    int lane = tid & 63;
    int w    = tid >> 6;
    int b    = blockIdx.x;
    int s    = b & 31;
    int g    = (b >> 5) * 4 + w;
    int i0   = g * 16;
    int q    = i0 >> 6;
    int n    = lane & 15;
    int quad = lane >> 4;
    int jbase = s * 128 + quad * 8;

    const int*      arow = adj + (size_t)(i0 + n) * N_NODES + jbase;
    const _Float16* prow = P + (size_t)q * N_NODES + jbase;
    const _Float16* hrow = hT + (size_t)n * N_NODES + jbase;

    // bounded preload: 8 adj dwordx4 + 4 P dwordx4 (48 VGPR) — all in flight together
    int4 a0[4], a1[4];
    half8 pv[4];
#pragma unroll
    for (int c = 0; c < 4; ++c) {
        a0[c] = *(const int4*)(arow + c * 32);
        a1[c] = *(const int4*)(arow + c * 32 + 4);
        pv[c] = *(const half8*)(prow + c * 32);
    }

    floatx4 acc[4] = {{0,0,0,0},{0,0,0,0},{0,0,0,0},{0,0,0,0}};
    floatx4 accd = {0, 0, 0, 0};
    _Float16 one_h = (n == 0) ? (_Float16)1.0f : (_Float16)0.0f;
    half8 ones_f = {one_h, one_h, one_h, one_h, one_h, one_h, one_h, one_h};

#pragma unroll
    for (int c = 0; c < 4; ++c) {
        int joff = c * 32;
        half8 af;
        af[0] = a0[c].x > 0 ? pv[c][0] : (_Float16)0.f;
        af[1] = a0[c].y > 0 ? pv[c][1] : (_Float16)0.f;
        af[2] = a0[c].z > 0 ? pv[c][2] : (_Float16)0.f;
        af[3] = a0[c].w > 0 ? pv[c][3] : (_Float16)0.f;
        af[4] = a1[c].x > 0 ? pv[c][4] : (_Float16)0.f;
        af[5] = a1[c].y > 0 ? pv[c][5] : (_Float16)0.f;
        af[6] = a1[c].z > 0 ? pv[c][6] : (_Float16)0.f;
        af[7] = a1[c].w > 0 ? pv[c][7] : (_Float16)0.f;
#pragma unroll
        for (int g4 = 0; g4 < 4; ++g4) {
            half8 bf = *(const half8*)(hrow + (size_t)g4 * 16 * N_NODES + joff);
            acc[g4] = __builtin_amdgcn_mfma_f32_16x16x32_f16(af, bf, acc[g4], 0, 0, 0);
        }
        accd = __builtin_amdgcn_mfma_f32_16x16x32_f16(af, ones_f, accd, 0, 0, 0);
    }
    // plain stores to this chunk's private partial
    float* op = out_part + ((size_t)s * N_NODES + i0) * F_OUT;
#pragma unroll
    for (int g4 = 0; g4 < 4; ++g4)
#pragma unroll
        for (int r = 0; r < 4; ++r)
            op[(quad * 4 + r) * F_OUT + g4 * 16 + n] = acc[g4][r];
    if (n == 0) {
#pragma unroll
        for (int r = 0; r < 4; ++r)
            den_part[s * N_NODES + i0 + quad * 4 + r] = accd[r];
    }
}

// ---------------- k_out: out = relu(sum_s out_part / sum_s den_part) + bias (float4) ----------------
__global__ __launch_bounds__(256) void k_out(const float* __restrict__ out_part,
                                             const float* __restrict__ den_part,
                                             const float* __restrict__ bias,
                                             float* __restrict__ out) {
    int idx4 = blockIdx.x * 256 + threadIdx.x;   // 65536 float4s
    int base = idx4 * 4;
    int i = base >> 6;
    int t = base & 63;
    float4 sacc = {0.f, 0.f, 0.f, 0.f};
    float dacc = 0.f;
#pragma unroll
    for (int p = 0; p < NPART; ++p) {
        float4 v = ((const float4*)(out_part + (size_t)p * N_NODES * F_OUT))[idx4];
        sacc.x += v.x; sacc.y += v.y; sacc.z += v.z; sacc.w += v.w;
        dacc += den_part[p * N_NODES + i];
    }
    float4 bv = *(const float4*)(bias + t);
    float4 o;
    o.x = fmaxf(sacc.x / dacc, 0.f) + bv.x;
    o.y = fmaxf(sacc.y / dacc, 0.f) + bv.y;
    o.z = fmaxf(sacc.z / dacc, 0.f) + bv.z;
    o.w = fmaxf(sacc.w / dacc, 0.f) + bv.w;
    ((float4*)out)[idx4] = o;
}

extern "C" void kernel_launch(void* const* d_in, const int* in_sizes, int n_in,
                              void* d_out, int out_size, void* d_ws, size_t ws_size,
                              hipStream_t stream) {
    const float* x    = (const float*)d_in[0];
    const int*   adj  = (const int*)d_in[1];
    const float* W    = (const float*)d_in[2];
    const float* a    = (const float*)d_in[3];
    const float* bias = (const float*)d_in[4];
    float* out = (float*)d_out;

    char* ws = (char*)d_ws;
    float*    h        = (float*)ws;                            // 1 MB
    _Float16* hT       = (_Float16*)(ws + 1024 * 1024);         // 512 KB
    float*    e1       = (float*)(ws + 1536 * 1024);            // 16 KB
    _Float16* P        = (_Float16*)(ws + 1552 * 1024);         // 512 KB
    _Float16* WT       = (_Float16*)(ws + 2064 * 1024);         // 64 KB
    float*    out_part = (float*)(ws + 2128 * 1024);            // 32 MB
    float*    den_part = (float*)(ws + (2128 + 32768) * 1024);  // 512 KB

    k_prep<<<128, 256, 0, stream>>>(W, WT);
    k_hW  <<<256, 256, 0, stream>>>(x, WT, a, h, hT, e1);
    k_TqP <<<64, 256, 0, stream>>>(h, a, e1, P);
    k_main<<<2048, 256, 0, stream>>>(adj, P, hT, out_part, den_part);
    k_out <<<256, 256, 0, stream>>>(out_part, den_part, bias, out);
}